// Round 13
// baseline (462.568 us; speedup 1.0000x reference)
//
#include <hip/hip_runtime.h>
#include <hip/hip_bf16.h>
#include <stdint.h>

typedef uint32_t u32;
typedef unsigned short u16;
typedef float v2f __attribute__((ext_vector_type(2)));

#define NLAT_I 361
#define NLON_I 720
#define NLAT_O 181
#define NLON_O 360
#define KK 9
#define NNZ 120000
#define NSEG (KK * NLAT_O)            /* 1629 */
#define NPIX (NLAT_O * NLON_O)        /* 65160 */
#define NCH 32
#define SORT_CAP 512
#define ROWLEN 5760                   /* u32 words per (hi,p) row: 360*16 */

/* stage1: 233 blocks x 7 sequential segs, 768 thr, launch_bounds(768,3).
   Law from r5..r12: time ~ 1/(waves x per-wave-in-flight-loads); the
   compiler will NOT keep a load burst live on its own (r12: VGPR=44,
   serialized) -- sched_barrier(0) between load cluster and FMA cluster
   forces all 16 dwordx4 into distinct VGPRs -> true depth-16. */
#define NBLK1 233
#define SEGS_PER_BLK 7
#define LDSCAP 160                    /* staged recs per segment (max cnt ~110) */
#define SPIN_LIMIT 100

__device__ __forceinline__ u32 f2bf_rne(float f) {
    u32 b = __float_as_uint(f);
    return (b + 0x7FFFu + ((b >> 16) & 1u)) >> 16;
}

__device__ __forceinline__ int imin(int a, int b) { return a < b ? a : b; }

// ---------------- repack: x[32][361][720] f32 -> xp[hi*2+p][j][cp] bf16x2 ---
__global__ __launch_bounds__(256) void repack_kernel(const float* __restrict__ x,
                                                     u32* __restrict__ xp) {
    __shared__ u16 tile[32][732];
    int hi = blockIdx.x;               // 361 blocks
    int tid = threadIdx.x;
    const size_t plane = (size_t)NLAT_I * NLON_I;
#pragma unroll 1
    for (int c = 0; c < NCH; c++) {
        for (int col = tid; col < NLON_I; col += 256) {
            tile[c][col] = (u16)f2bf_rne(x[c * plane + (size_t)hi * NLON_I + col]);
        }
    }
    __syncthreads();
    for (int wdx = tid; wdx < 2 * ROWLEN; wdx += 256) {
        int p = wdx / ROWLEN;
        int rem = wdx - p * ROWLEN;
        int j = rem >> 4;
        int cp = rem & 15;
        int col = 2 * j + p;
        u32 v = (u32)tile[2 * cp][col] | ((u32)tile[2 * cp + 1][col] << 16);
        xp[(size_t)(2 * hi + p) * ROWLEN + rem] = v;
    }
}

// ---------------- CSR build ------------------------------------------------
__global__ __launch_bounds__(256) void hist_kernel(const int* __restrict__ ker,
                                                   const int* __restrict__ row,
                                                   int* __restrict__ counts) {
    int e = blockIdx.x * 256 + threadIdx.x;
    if (e >= NNZ) return;
    int seg = ker[e] * NLAT_O + row[e];
    atomicAdd(&counts[seg], 1);
}

__global__ __launch_bounds__(256) void scan_kernel(const int* __restrict__ counts,
                                                   int* __restrict__ offsets) {
    __shared__ int lsum[256];
    const int CH = 7;                  // 256*7 = 1792 >= 1629
    int t = threadIdx.x;
    int base = t * CH;
    int local[CH];
    int s = 0;
    for (int i = 0; i < CH; i++) {
        int v = (base + i < NSEG) ? counts[base + i] : 0;
        local[i] = s;
        s += v;
    }
    lsum[t] = s;
    __syncthreads();
    for (int off = 1; off < 256; off <<= 1) {
        int v = 0;
        if (t >= off) v = lsum[t - off];
        __syncthreads();
        if (t >= off) lsum[t] += v;
        __syncthreads();
    }
    int pre = (t == 0) ? 0 : lsum[t - 1];
    for (int i = 0; i < CH; i++) {
        if (base + i < NSEG) offsets[base + i] = pre + local[i];
    }
}

__global__ __launch_bounds__(256) void scatter_kernel(const int* __restrict__ ker,
                                                      const int* __restrict__ row,
                                                      const int* __restrict__ col,
                                                      const float* __restrict__ vals,
                                                      const int* __restrict__ offsets,
                                                      int* __restrict__ cursor,
                                                      int2* __restrict__ recs) {
    int e = blockIdx.x * 256 + threadIdx.x;
    if (e >= NNZ) return;
    int seg = ker[e] * NLAT_O + row[e];
    int pos = offsets[seg] + atomicAdd(&cursor[seg], 1);
    int c  = col[e];
    int hi = c / NLON_I;
    int wi = c % NLON_I;
    int p  = wi & 1;
    int a  = wi >> 1;                  // < 360
    u32 meta = ((u32)hi << 10) | ((u32)p << 9) | (u32)a;
    recs[pos] = make_int2((int)meta, __float_as_int(vals[e]));
}

// ---------------- per-segment sort by meta (hi,p,a ascending) --------------
__global__ __launch_bounds__(256) void sort_kernel(const int* __restrict__ offs,
                                                   const int* __restrict__ cnts,
                                                   int2* __restrict__ recs) {
    __shared__ u32 skey[SORT_CAP];
    __shared__ u32 sval[SORT_CAP];
    int s = blockIdx.x;
    int start = offs[s];
    int cnt = cnts[s];
    if (cnt > SORT_CAP) return;       // perf-only transform; safe to skip
    int t = threadIdx.x;
    for (int i = t; i < cnt; i += 256) {
        int2 r = recs[start + i];
        skey[i] = (u32)r.x;
        sval[i] = (u32)r.y;
    }
    __syncthreads();
    for (int i = t; i < cnt; i += 256) {
        u32 k = skey[i];
        int rank = 0;
        for (int j = 0; j < cnt; j++) {
            u32 kj = skey[j];
            rank += (kj < k || (kj == k && j < i)) ? 1 : 0;
        }
        recs[start + rank] = make_int2((int)k, (int)sval[i]);
    }
}

// ---------------- stage1 ---------------------------------------------------
__device__ __forceinline__ v2f bf2(u32 u) {
    v2f r;
    r.x = __uint_as_float(u << 16);
    r.y = __uint_as_float(u & 0xFFFF0000u);
    return r;
}

__device__ __forceinline__ const uint4* entry_ptr(const u32* __restrict__ xph,
                                                  u32 m, int w) {
    int row = (int)(m >> 9);            // hi*2+p
    int a   = (int)(m & 0x1FF);
    int idx = a + w;
    idx = (idx >= NLON_O) ? idx - NLON_O : idx;
    return (const uint4*)(xph + ((size_t)(row * NLON_O + idx) << 4));
}

#define FMA8(q0, q1, vv, A)                 \
    {                                       \
        A[0] = bf2(q0.x) * vv + A[0];       \
        A[1] = bf2(q0.y) * vv + A[1];       \
        A[2] = bf2(q0.z) * vv + A[2];       \
        A[3] = bf2(q0.w) * vv + A[3];       \
        A[4] = bf2(q1.x) * vv + A[4];       \
        A[5] = bf2(q1.y) * vv + A[5];       \
        A[6] = bf2(q1.z) * vv + A[6];       \
        A[7] = bf2(q1.w) * vv + A[7];       \
    }

__device__ __forceinline__ void proc_range(const u32* __restrict__ xph,
                                           const int2* __restrict__ rec,
                                           int beg, int end, int w,
                                           v2f* __restrict__ A) {
    int i = beg;
    // burst-8: 16 dwordx4 issued BEFORE any consumer. sched_barrier(0)
    // fences loads above / FMAs below, forcing 64 distinct dest VGPRs ->
    // true in-flight depth 16 (r12 without fence: compiler serialized to
    // VGPR_Count=44, effective depth ~2).
#pragma unroll 1
    for (; i + 8 <= end; i += 8) {
        int2 r0 = rec[i];     int2 r1 = rec[i + 1];
        int2 r2 = rec[i + 2]; int2 r3 = rec[i + 3];
        int2 r4 = rec[i + 4]; int2 r5 = rec[i + 5];
        int2 r6 = rec[i + 6]; int2 r7 = rec[i + 7];
        const uint4* p0 = entry_ptr(xph, (u32)r0.x, w);
        const uint4* p1 = entry_ptr(xph, (u32)r1.x, w);
        const uint4* p2 = entry_ptr(xph, (u32)r2.x, w);
        const uint4* p3 = entry_ptr(xph, (u32)r3.x, w);
        const uint4* p4 = entry_ptr(xph, (u32)r4.x, w);
        const uint4* p5 = entry_ptr(xph, (u32)r5.x, w);
        const uint4* p6 = entry_ptr(xph, (u32)r6.x, w);
        const uint4* p7 = entry_ptr(xph, (u32)r7.x, w);
        uint4 a0 = p0[0]; uint4 a1 = p0[1];
        uint4 b0 = p1[0]; uint4 b1 = p1[1];
        uint4 c0 = p2[0]; uint4 c1 = p2[1];
        uint4 d0 = p3[0]; uint4 d1 = p3[1];
        uint4 e0 = p4[0]; uint4 e1 = p4[1];
        uint4 f0 = p5[0]; uint4 f1 = p5[1];
        uint4 g0 = p6[0]; uint4 g1 = p6[1];
        uint4 h0 = p7[0]; uint4 h1 = p7[1];
        __builtin_amdgcn_sched_barrier(0);
        v2f v0 = {__int_as_float(r0.y), __int_as_float(r0.y)};
        v2f v1 = {__int_as_float(r1.y), __int_as_float(r1.y)};
        v2f v2 = {__int_as_float(r2.y), __int_as_float(r2.y)};
        v2f v3 = {__int_as_float(r3.y), __int_as_float(r3.y)};
        v2f v4 = {__int_as_float(r4.y), __int_as_float(r4.y)};
        v2f v5 = {__int_as_float(r5.y), __int_as_float(r5.y)};
        v2f v6 = {__int_as_float(r6.y), __int_as_float(r6.y)};
        v2f v7 = {__int_as_float(r7.y), __int_as_float(r7.y)};
        FMA8(a0, a1, v0, A)
        FMA8(b0, b1, v1, A)
        FMA8(c0, c1, v2, A)
        FMA8(d0, d1, v3, A)
        FMA8(e0, e1, v4, A)
        FMA8(f0, f1, v5, A)
        FMA8(g0, g1, v6, A)
        FMA8(h0, h1, v7, A)
    }
#pragma unroll 1
    for (; i + 4 <= end; i += 4) {
        int2 r0 = rec[i];
        int2 r1 = rec[i + 1];
        int2 r2 = rec[i + 2];
        int2 r3 = rec[i + 3];
        const uint4* p0 = entry_ptr(xph, (u32)r0.x, w);
        const uint4* p1 = entry_ptr(xph, (u32)r1.x, w);
        const uint4* p2 = entry_ptr(xph, (u32)r2.x, w);
        const uint4* p3 = entry_ptr(xph, (u32)r3.x, w);
        uint4 a0 = p0[0]; uint4 a1 = p0[1];
        uint4 b0 = p1[0]; uint4 b1 = p1[1];
        uint4 c0 = p2[0]; uint4 c1 = p2[1];
        uint4 d0 = p3[0]; uint4 d1 = p3[1];
        __builtin_amdgcn_sched_barrier(0);
        v2f v0 = {__int_as_float(r0.y), __int_as_float(r0.y)};
        v2f v1 = {__int_as_float(r1.y), __int_as_float(r1.y)};
        v2f v2 = {__int_as_float(r2.y), __int_as_float(r2.y)};
        v2f v3 = {__int_as_float(r3.y), __int_as_float(r3.y)};
        FMA8(a0, a1, v0, A)
        FMA8(b0, b1, v1, A)
        FMA8(c0, c1, v2, A)
        FMA8(d0, d1, v3, A)
    }
#pragma unroll 1
    for (; i < end; ++i) {
        int2 r0 = rec[i];
        const uint4* p0 = entry_ptr(xph, (u32)r0.x, w);
        uint4 a0 = p0[0]; uint4 a1 = p0[1];
        v2f v0 = {__int_as_float(r0.y), __int_as_float(r0.y)};
        FMA8(a0, a1, v0, A)
    }
}

__global__ __launch_bounds__(768, 3) void stage1_kernel(const u32* __restrict__ xp,
                                                        const int* __restrict__ offs,
                                                        const int* __restrict__ cnts,
                                                        const int2* __restrict__ recs,
                                                        int* __restrict__ ctr,
                                                        u16* __restrict__ xk) {
    __shared__ int2 lrec[SEGS_PER_BLK][LDSCAP];
    __shared__ int scnt[SEGS_PER_BLK], soff[SEGS_PER_BLK];

    int b = blockIdx.x;
    int tid = threadIdx.x;

    if (tid < SEGS_PER_BLK) {
        int s = b * SEGS_PER_BLK + tid;
        int ok = (s < NSEG);
        scnt[tid] = ok ? cnts[s] : 0;
        soff[tid] = ok ? offs[s] : 0;
    }
    __syncthreads();

#pragma unroll
    for (int slot = 0; slot < SEGS_PER_BLK; slot++) {
        int c = imin(scnt[slot], LDSCAP);
        int o = soff[slot];
        for (int i = tid; i < c; i += 768) lrec[slot][i] = recs[o + i];
    }
    __syncthreads();

    int wo = tid >> 1, h = tid & 1;
    bool act = wo < NLON_O;
    int w = act ? wo : 0;
    const u32* xph = xp + h * 8;

#pragma unroll 1
    for (int t = 0; t < SEGS_PER_BLK; t++) {
        v2f acc[8];
#pragma unroll
        for (int j = 0; j < 8; j++) acc[j] = (v2f){0.0f, 0.0f};

        int cnt = scnt[t];
        int lim = imin(cnt, LDSCAP);
        proc_range(xph, lrec[t], 0, lim, w, acc);
        if (cnt > LDSCAP)              // overflow safety net (cnt ~74 typ.)
            proc_range(xph, recs + soff[t], LDSCAP, cnt, w, acc);

        int s = b * SEGS_PER_BLK + t;
        if (act && s < NSEG) {
            int k = s / NLAT_O;
            int ho = s - k * NLAT_O;
            int pix = ho * NLON_O + wo;
#pragma unroll
            for (int j = 0; j < 8; j++) {
                int ch = h * 16 + 2 * j;
                xk[(size_t)(ch * KK + k) * NPIX + pix] = (u16)f2bf_rne(acc[j].x);
                xk[(size_t)((ch + 1) * KK + k) * NPIX + pix] = (u16)f2bf_rne(acc[j].y);
            }
        }

        if (t == 1 || t == 3 || t == 5) {
            // quasi-barrier every 2 seg-slots: keeps co-resident blocks'
            // sorted-hi sweeps aligned (L2 window). Deadlock-free: spin
            // capped; correctness never depends on it.
            __syncthreads();
            if (tid == 0) {
                int ci = t >> 1;
                __hip_atomic_fetch_add(&ctr[ci], 1, __ATOMIC_RELAXED,
                                       __HIP_MEMORY_SCOPE_AGENT);
                int spins = 0;
                while (spins < SPIN_LIMIT &&
                       __hip_atomic_load(&ctr[ci], __ATOMIC_RELAXED,
                                         __HIP_MEMORY_SCOPE_AGENT) < (int)gridDim.x) {
                    __builtin_amdgcn_s_sleep(2);
                    ++spins;
                }
            }
            __syncthreads();
        }
    }
}

// ---------------- stage2: out[32][65160] = W[32][288] * xk[288][65160] -----
// K-split x4: block = 64 pix-pairs x 4 K-slices (72 r each), LDS reduce.
#define S2_PP 64
#define S2_RPK 72                     /* 288 / 4 */

__global__ __launch_bounds__(256) void stage2_kernel(const u16* __restrict__ xk,
                                                     const float* __restrict__ W,
                                                     const float* __restrict__ bias,
                                                     float* __restrict__ out) {
    __shared__ float2 red[4][S2_PP][17];   // 4*64*17*8 = 34816 B
    int pp  = threadIdx.x & 63;
    int ksl = threadIdx.x >> 6;            // 0..3
    int px2 = blockIdx.x * S2_PP + pp;     // pix-pair id
    bool act = px2 < NPIX / 2;
    int px = act ? px2 : 0;
    const u32* xk32 = (const u32*)xk;

    float a0[NCH], a1[NCH];
#pragma unroll
    for (int o = 0; o < NCH; o++) { a0[o] = 0.0f; a1[o] = 0.0f; }

    int rbase = ksl * S2_RPK;
#pragma unroll 4
    for (int rr = 0; rr < S2_RPK; rr++) {
        int r = rbase + rr;
        u32 u = xk32[(size_t)r * (NPIX / 2) + px];
        float x0 = __uint_as_float(u << 16);
        float x1 = __uint_as_float(u & 0xFFFF0000u);
#pragma unroll
        for (int o = 0; o < NCH; o++) {
            float wv = W[o * (NCH * KK) + r];
            a0[o] = fmaf(wv, x0, a0[o]);
            a1[o] = fmaf(wv, x1, a1[o]);
        }
    }

    // reduce the 4 K-slices via LDS, in 2 half-passes of 16 outputs each
#pragma unroll 1
    for (int half = 0; half < 2; half++) {
        __syncthreads();
#pragma unroll
        for (int j = 0; j < 16; j++) {
            int o = half * 16 + j;
            red[ksl][pp][j] = make_float2(a0[o], a1[o]);
        }
        __syncthreads();
        // wave ksl now handles outputs [ksl*4, ksl*4+4) of this half
#pragma unroll
        for (int j = 0; j < 4; j++) {
            int oo = ksl * 4 + j;
            float2 s0 = red[0][pp][oo];
            float2 s1 = red[1][pp][oo];
            float2 s2 = red[2][pp][oo];
            float2 s3 = red[3][pp][oo];
            float sx = s0.x + s1.x + s2.x + s3.x;
            float sy = s0.y + s1.y + s2.y + s3.y;
            int o = half * 16 + oo;
            if (act) {
                float bv = bias[o];
                float2 v = make_float2(sx + bv, sy + bv);
                *(float2*)(out + (size_t)o * NPIX + 2 * px2) = v;
            }
        }
    }
}

// ---------------- launch ---------------------------------------------------
extern "C" void kernel_launch(void* const* d_in, const int* in_sizes, int n_in,
                              void* d_out, int out_size, void* d_ws, size_t ws_size,
                              hipStream_t stream) {
    const float* x    = (const float*)d_in[0];
    const int* ker    = (const int*)d_in[1];
    const int* row    = (const int*)d_in[2];
    const int* col    = (const int*)d_in[3];
    const float* vals = (const float*)d_in[4];
    const float* W    = (const float*)d_in[5];
    const float* bias = (const float*)d_in[6];
    float* out        = (float*)d_out;

    char* ws = (char*)d_ws;
    const size_t off_xp   = 0;
    const size_t sz_xp    = (size_t)NLAT_I * 2 * ROWLEN * 4;   // 16,634,880
    const size_t off_cnt  = off_xp + sz_xp;
    const size_t off_off  = off_cnt + 6528;
    const size_t off_cur  = off_off + 6528;
    const size_t off_ctr  = off_cur + 6528;                    // 64 B (ctr ints)
    const size_t off_rec  = off_ctr + 64;                      // 8-aligned
    const size_t off_xk   = off_rec + (size_t)NNZ * 8;

    u32* xp      = (u32*)(ws + off_xp);
    int* counts  = (int*)(ws + off_cnt);
    int* offsets = (int*)(ws + off_off);
    int* cursor  = (int*)(ws + off_cur);
    int* ctr     = (int*)(ws + off_ctr);
    int2* recs   = (int2*)(ws + off_rec);
    u16* xk      = (u16*)(ws + off_xk);

    // zero counts + offsets + cursor + barrier counters
    hipMemsetAsync(ws + off_cnt, 0, 3 * 6528 + 64, stream);

    repack_kernel<<<NLAT_I, 256, 0, stream>>>(x, xp);
    hist_kernel<<<(NNZ + 255) / 256, 256, 0, stream>>>(ker, row, counts);
    scan_kernel<<<1, 256, 0, stream>>>(counts, offsets);
    scatter_kernel<<<(NNZ + 255) / 256, 256, 0, stream>>>(ker, row, col, vals,
                                                          offsets, cursor, recs);
    sort_kernel<<<NSEG, 256, 0, stream>>>(offsets, counts, recs);
    stage1_kernel<<<NBLK1, 768, 0, stream>>>(xp, offsets, counts, recs, ctr, xk);
    stage2_kernel<<<(NPIX / 2 + S2_PP - 1) / S2_PP, 256, 0, stream>>>(xk, W, bias, out);
}

// Round 14
// 349.386 us; speedup vs baseline: 1.3239x; 1.3239x over previous
//
#include <hip/hip_runtime.h>
#include <hip/hip_bf16.h>
#include <stdint.h>

typedef uint32_t u32;
typedef unsigned short u16;
typedef float v2f __attribute__((ext_vector_type(2)));

#define NLAT_I 361
#define NLON_I 720
#define NLAT_O 181
#define NLON_O 360
#define KK 9
#define NNZ 120000
#define NSEG (KK * NLAT_O)            /* 1629 */
#define NPIX (NLAT_O * NLON_O)        /* 65160 */
#define NCH 32
#define SORT_CAP 512
#define ROWLEN 5760                   /* u32 words per (hi,p) row: 360*16 */

/* stage1: r9 structure (parallel acc[7][8], burst-4, NC=4 phases) -- the
   measured optimum (220 us). Geometry rebalanced 233->256 blocks so no CU
   idles: blocks 0..92 own 7 segs, 93..255 own 6 (93*7+163*6=1629). */
#define NBLK1 256
#define RBLK 93
#define MAXS 7
#define NC 4                          /* sorted-hi phases (r9/r10: optimum) */
#define LDSCAP 160                    /* staged recs per segment (max cnt ~110) */
#define SPIN_LIMIT 100

__device__ __forceinline__ u32 f2bf_rne(float f) {
    u32 b = __float_as_uint(f);
    return (b + 0x7FFFu + ((b >> 16) & 1u)) >> 16;
}

__device__ __forceinline__ int imin(int a, int b) { return a < b ? a : b; }

// ---------------- repack: x[32][361][720] f32 -> xp[hi*2+p][j][cp] bf16x2 ---
// Block 0 additionally zeroes counts/cursor/ctr (replaces the memset
// dispatch; stream order guarantees completion before hist/scatter/stage1).
__global__ __launch_bounds__(256) void repack_kernel(const float* __restrict__ x,
                                                     u32* __restrict__ xp,
                                                     int* __restrict__ counts,
                                                     int* __restrict__ cursor,
                                                     int* __restrict__ ctr) {
    __shared__ u16 tile[32][732];
    int hi = blockIdx.x;               // 361 blocks
    int tid = threadIdx.x;
    if (hi == 0) {
        for (int i = tid; i < 1632; i += 256) { counts[i] = 0; cursor[i] = 0; }
        if (tid < 16) ctr[tid] = 0;
    }
    const size_t plane = (size_t)NLAT_I * NLON_I;
#pragma unroll 1
    for (int c = 0; c < NCH; c++) {
        for (int col = tid; col < NLON_I; col += 256) {
            tile[c][col] = (u16)f2bf_rne(x[c * plane + (size_t)hi * NLON_I + col]);
        }
    }
    __syncthreads();
    for (int wdx = tid; wdx < 2 * ROWLEN; wdx += 256) {
        int p = wdx / ROWLEN;
        int rem = wdx - p * ROWLEN;
        int j = rem >> 4;
        int cp = rem & 15;
        int col = 2 * j + p;
        u32 v = (u32)tile[2 * cp][col] | ((u32)tile[2 * cp + 1][col] << 16);
        xp[(size_t)(2 * hi + p) * ROWLEN + rem] = v;
    }
}

// ---------------- CSR build ------------------------------------------------
__global__ __launch_bounds__(256) void hist_kernel(const int* __restrict__ ker,
                                                   const int* __restrict__ row,
                                                   int* __restrict__ counts) {
    int e = blockIdx.x * 256 + threadIdx.x;
    if (e >= NNZ) return;
    int seg = ker[e] * NLAT_O + row[e];
    atomicAdd(&counts[seg], 1);
}

__global__ __launch_bounds__(256) void scan_kernel(const int* __restrict__ counts,
                                                   int* __restrict__ offsets) {
    __shared__ int lsum[256];
    const int CH = 7;                  // 256*7 = 1792 >= 1629
    int t = threadIdx.x;
    int base = t * CH;
    int local[CH];
    int s = 0;
    for (int i = 0; i < CH; i++) {
        int v = (base + i < NSEG) ? counts[base + i] : 0;
        local[i] = s;
        s += v;
    }
    lsum[t] = s;
    __syncthreads();
    for (int off = 1; off < 256; off <<= 1) {
        int v = 0;
        if (t >= off) v = lsum[t - off];
        __syncthreads();
        if (t >= off) lsum[t] += v;
        __syncthreads();
    }
    int pre = (t == 0) ? 0 : lsum[t - 1];
    for (int i = 0; i < CH; i++) {
        if (base + i < NSEG) offsets[base + i] = pre + local[i];
    }
}

__global__ __launch_bounds__(256) void scatter_kernel(const int* __restrict__ ker,
                                                      const int* __restrict__ row,
                                                      const int* __restrict__ col,
                                                      const float* __restrict__ vals,
                                                      const int* __restrict__ offsets,
                                                      int* __restrict__ cursor,
                                                      int2* __restrict__ recs) {
    int e = blockIdx.x * 256 + threadIdx.x;
    if (e >= NNZ) return;
    int seg = ker[e] * NLAT_O + row[e];
    int pos = offsets[seg] + atomicAdd(&cursor[seg], 1);
    int c  = col[e];
    int hi = c / NLON_I;
    int wi = c % NLON_I;
    int p  = wi & 1;
    int a  = wi >> 1;                  // < 360
    u32 meta = ((u32)hi << 10) | ((u32)p << 9) | (u32)a;
    recs[pos] = make_int2((int)meta, __float_as_int(vals[e]));
}

// ---------------- per-segment sort by meta (hi,p,a ascending) --------------
__global__ __launch_bounds__(256) void sort_kernel(const int* __restrict__ offs,
                                                   const int* __restrict__ cnts,
                                                   int2* __restrict__ recs) {
    __shared__ u32 skey[SORT_CAP];
    __shared__ u32 sval[SORT_CAP];
    int s = blockIdx.x;
    int start = offs[s];
    int cnt = cnts[s];
    if (cnt > SORT_CAP) return;       // perf-only transform; safe to skip
    int t = threadIdx.x;
    for (int i = t; i < cnt; i += 256) {
        int2 r = recs[start + i];
        skey[i] = (u32)r.x;
        sval[i] = (u32)r.y;
    }
    __syncthreads();
    for (int i = t; i < cnt; i += 256) {
        u32 k = skey[i];
        int rank = 0;
        for (int j = 0; j < cnt; j++) {
            u32 kj = skey[j];
            rank += (kj < k || (kj == k && j < i)) ? 1 : 0;
        }
        recs[start + rank] = make_int2((int)k, (int)sval[i]);
    }
}

// ---------------- stage1: persistent, channel-split, phase-synced ----------
// thread = (wo, channel-half). acc = v2f[7][8] (112 f32, AGPR half of the
// unified file). Inner loop: burst unroll-4 (8 independent dwordx4 in
// flight). DO NOT: rotate-pipeline (r8 spill), launch_bounds(,6) (r11 reg
// starve), burst-8 (r12 serialized), sched_barrier fence (r13 regression).
// This exact structure+NC4 measured 220 us.

__device__ __forceinline__ v2f bf2(u32 u) {
    v2f r;
    r.x = __uint_as_float(u << 16);
    r.y = __uint_as_float(u & 0xFFFF0000u);
    return r;
}

__device__ __forceinline__ const uint4* entry_ptr(const u32* __restrict__ xph,
                                                  u32 m, int w) {
    int row = (int)(m >> 9);            // hi*2+p
    int a   = (int)(m & 0x1FF);
    int idx = a + w;
    idx = (idx >= NLON_O) ? idx - NLON_O : idx;
    return (const uint4*)(xph + ((size_t)(row * NLON_O + idx) << 4));
}

#define FMA8(q0, q1, vv, A)                 \
    {                                       \
        A[0] = bf2(q0.x) * vv + A[0];       \
        A[1] = bf2(q0.y) * vv + A[1];       \
        A[2] = bf2(q0.z) * vv + A[2];       \
        A[3] = bf2(q0.w) * vv + A[3];       \
        A[4] = bf2(q1.x) * vv + A[4];       \
        A[5] = bf2(q1.y) * vv + A[5];       \
        A[6] = bf2(q1.z) * vv + A[6];       \
        A[7] = bf2(q1.w) * vv + A[7];       \
    }

__device__ __forceinline__ void proc_range(const u32* __restrict__ xph,
                                           const int2* __restrict__ rec,
                                           int beg, int end, int w,
                                           v2f* __restrict__ A) {
    int i = beg;
#pragma unroll 1
    for (; i + 4 <= end; i += 4) {
        int2 r0 = rec[i];
        int2 r1 = rec[i + 1];
        int2 r2 = rec[i + 2];
        int2 r3 = rec[i + 3];
        const uint4* p0 = entry_ptr(xph, (u32)r0.x, w);
        const uint4* p1 = entry_ptr(xph, (u32)r1.x, w);
        const uint4* p2 = entry_ptr(xph, (u32)r2.x, w);
        const uint4* p3 = entry_ptr(xph, (u32)r3.x, w);
        uint4 a0 = p0[0]; uint4 a1 = p0[1];
        uint4 b0 = p1[0]; uint4 b1 = p1[1];
        uint4 c0 = p2[0]; uint4 c1 = p2[1];
        uint4 d0 = p3[0]; uint4 d1 = p3[1];
        v2f v0 = {__int_as_float(r0.y), __int_as_float(r0.y)};
        v2f v1 = {__int_as_float(r1.y), __int_as_float(r1.y)};
        v2f v2 = {__int_as_float(r2.y), __int_as_float(r2.y)};
        v2f v3 = {__int_as_float(r3.y), __int_as_float(r3.y)};
        FMA8(a0, a1, v0, A)
        FMA8(b0, b1, v1, A)
        FMA8(c0, c1, v2, A)
        FMA8(d0, d1, v3, A)
    }
#pragma unroll 1
    for (; i < end; ++i) {
        int2 r0 = rec[i];
        const uint4* p0 = entry_ptr(xph, (u32)r0.x, w);
        uint4 a0 = p0[0]; uint4 a1 = p0[1];
        v2f v0 = {__int_as_float(r0.y), __int_as_float(r0.y)};
        FMA8(a0, a1, v0, A)
    }
}

__global__ __launch_bounds__(768, 3) void stage1_kernel(const u32* __restrict__ xp,
                                                        const int* __restrict__ offs,
                                                        const int* __restrict__ cnts,
                                                        const int2* __restrict__ recs,
                                                        int* __restrict__ ctr,
                                                        u16* __restrict__ xk) {
    __shared__ int2 lrec[MAXS][LDSCAP];
    __shared__ int scnt[MAXS], soff[MAXS];

    int b = blockIdx.x;
    int tid = threadIdx.x;
    int nb = (b < RBLK) ? 7 : 6;
    int start = (b < RBLK) ? b * 7 : RBLK * 7 + (b - RBLK) * 6;

    if (tid < MAXS) {
        int s = start + tid;
        int ok = (tid < nb) && (s < NSEG);
        scnt[tid] = ok ? cnts[s] : 0;
        soff[tid] = ok ? offs[s] : 0;
    }
    __syncthreads();

#pragma unroll
    for (int slot = 0; slot < MAXS; slot++) {
        int c = imin(scnt[slot], LDSCAP);
        int o = soff[slot];
        for (int i = tid; i < c; i += 768) lrec[slot][i] = recs[o + i];
    }
    __syncthreads();

    int wo = tid >> 1, h = tid & 1;
    bool act = wo < NLON_O;
    int w = act ? wo : 0;
    const u32* xph = xp + h * 8;

    v2f acc[MAXS][8];
#pragma unroll
    for (int slot = 0; slot < MAXS; slot++)
#pragma unroll
        for (int j = 0; j < 8; j++) acc[slot][j] = (v2f){0.0f, 0.0f};

    for (int c = 0; c < NC; c++) {
#pragma unroll
        for (int slot = 0; slot < MAXS; slot++) {
            int cnt = scnt[slot];
            int beg = (c * cnt) / NC;
            int end = ((c + 1) * cnt) / NC;
            if (end <= LDSCAP) {
                proc_range(xph, lrec[slot], beg, end, w, acc[slot]);
            } else {
                proc_range(xph, recs + soff[slot], beg, end, w, acc[slot]);
            }
        }
        if (c < NC - 1) {
            // bounded-spin quasi-barrier: keeps all co-resident blocks on the
            // same sorted-hi chunk (~4 MB live xp slice -> per-XCD L2 hot).
            // Deadlock-free: spin capped; correctness never depends on it.
            __syncthreads();
            if (tid == 0) {
                __hip_atomic_fetch_add(&ctr[c], 1, __ATOMIC_RELAXED,
                                       __HIP_MEMORY_SCOPE_AGENT);
                int spins = 0;
                while (spins < SPIN_LIMIT &&
                       __hip_atomic_load(&ctr[c], __ATOMIC_RELAXED,
                                         __HIP_MEMORY_SCOPE_AGENT) < (int)gridDim.x) {
                    __builtin_amdgcn_s_sleep(2);
                    ++spins;
                }
            }
            __syncthreads();
        }
    }

    if (act) {
#pragma unroll
        for (int slot = 0; slot < MAXS; slot++) {
            int s = start + slot;
            // guard slot<nb: a 6-seg block's slot 6 aliases the NEXT block's
            // first segment -- must not write it.
            if (slot < nb && s < NSEG) {
                int k = s / NLAT_O;
                int ho = s - k * NLAT_O;
                int pix = ho * NLON_O + wo;
#pragma unroll
                for (int j = 0; j < 8; j++) {
                    int ch = h * 16 + 2 * j;
                    xk[(size_t)(ch * KK + k) * NPIX + pix] =
                        (u16)f2bf_rne(acc[slot][j].x);
                    xk[(size_t)((ch + 1) * KK + k) * NPIX + pix] =
                        (u16)f2bf_rne(acc[slot][j].y);
                }
            }
        }
    }
}

// ---------------- stage2: out[32][65160] = W[32][288] * xk[288][65160] -----
// K-split x4: block = 64 pix-pairs x 4 K-slices (72 r each), LDS reduce.
#define S2_PP 64
#define S2_RPK 72                     /* 288 / 4 */

__global__ __launch_bounds__(256) void stage2_kernel(const u16* __restrict__ xk,
                                                     const float* __restrict__ W,
                                                     const float* __restrict__ bias,
                                                     float* __restrict__ out) {
    __shared__ float2 red[4][S2_PP][17];   // 4*64*17*8 = 34816 B
    int pp  = threadIdx.x & 63;
    int ksl = threadIdx.x >> 6;            // 0..3
    int px2 = blockIdx.x * S2_PP + pp;     // pix-pair id
    bool act = px2 < NPIX / 2;
    int px = act ? px2 : 0;
    const u32* xk32 = (const u32*)xk;

    float a0[NCH], a1[NCH];
#pragma unroll
    for (int o = 0; o < NCH; o++) { a0[o] = 0.0f; a1[o] = 0.0f; }

    int rbase = ksl * S2_RPK;
#pragma unroll 4
    for (int rr = 0; rr < S2_RPK; rr++) {
        int r = rbase + rr;
        u32 u = xk32[(size_t)r * (NPIX / 2) + px];
        float x0 = __uint_as_float(u << 16);
        float x1 = __uint_as_float(u & 0xFFFF0000u);
#pragma unroll
        for (int o = 0; o < NCH; o++) {
            float wv = W[o * (NCH * KK) + r];
            a0[o] = fmaf(wv, x0, a0[o]);
            a1[o] = fmaf(wv, x1, a1[o]);
        }
    }

    // reduce the 4 K-slices via LDS, in 2 half-passes of 16 outputs each
#pragma unroll 1
    for (int half = 0; half < 2; half++) {
        __syncthreads();
#pragma unroll
        for (int j = 0; j < 16; j++) {
            int o = half * 16 + j;
            red[ksl][pp][j] = make_float2(a0[o], a1[o]);
        }
        __syncthreads();
        // wave ksl now handles outputs [ksl*4, ksl*4+4) of this half
#pragma unroll
        for (int j = 0; j < 4; j++) {
            int oo = ksl * 4 + j;
            float2 s0 = red[0][pp][oo];
            float2 s1 = red[1][pp][oo];
            float2 s2 = red[2][pp][oo];
            float2 s3 = red[3][pp][oo];
            float sx = s0.x + s1.x + s2.x + s3.x;
            float sy = s0.y + s1.y + s2.y + s3.y;
            int o = half * 16 + oo;
            if (act) {
                float bv = bias[o];
                float2 v = make_float2(sx + bv, sy + bv);
                *(float2*)(out + (size_t)o * NPIX + 2 * px2) = v;
            }
        }
    }
}

// ---------------- launch ---------------------------------------------------
extern "C" void kernel_launch(void* const* d_in, const int* in_sizes, int n_in,
                              void* d_out, int out_size, void* d_ws, size_t ws_size,
                              hipStream_t stream) {
    const float* x    = (const float*)d_in[0];
    const int* ker    = (const int*)d_in[1];
    const int* row    = (const int*)d_in[2];
    const int* col    = (const int*)d_in[3];
    const float* vals = (const float*)d_in[4];
    const float* W    = (const float*)d_in[5];
    const float* bias = (const float*)d_in[6];
    float* out        = (float*)d_out;

    char* ws = (char*)d_ws;
    const size_t off_xp   = 0;
    const size_t sz_xp    = (size_t)NLAT_I * 2 * ROWLEN * 4;   // 16,634,880
    const size_t off_cnt  = off_xp + sz_xp;
    const size_t off_off  = off_cnt + 6528;
    const size_t off_cur  = off_off + 6528;
    const size_t off_ctr  = off_cur + 6528;                    // 64 B (ctr ints)
    const size_t off_rec  = off_ctr + 64;                      // 8-aligned
    const size_t off_xk   = off_rec + (size_t)NNZ * 8;

    u32* xp      = (u32*)(ws + off_xp);
    int* counts  = (int*)(ws + off_cnt);
    int* offsets = (int*)(ws + off_off);
    int* cursor  = (int*)(ws + off_cur);
    int* ctr     = (int*)(ws + off_ctr);
    int2* recs   = (int2*)(ws + off_rec);
    u16* xk      = (u16*)(ws + off_xk);

    // zeroing of counts/cursor/ctr is folded into repack_kernel block 0
    repack_kernel<<<NLAT_I, 256, 0, stream>>>(x, xp, counts, cursor, ctr);
    hist_kernel<<<(NNZ + 255) / 256, 256, 0, stream>>>(ker, row, counts);
    scan_kernel<<<1, 256, 0, stream>>>(counts, offsets);
    scatter_kernel<<<(NNZ + 255) / 256, 256, 0, stream>>>(ker, row, col, vals,
                                                          offsets, cursor, recs);
    sort_kernel<<<NSEG, 256, 0, stream>>>(offsets, counts, recs);
    stage1_kernel<<<NBLK1, 768, 0, stream>>>(xp, offsets, counts, recs, ctr, xk);
    stage2_kernel<<<(NPIX / 2 + S2_PP - 1) / S2_PP, 256, 0, stream>>>(xk, W, bias, out);
}

// Round 15
// 345.920 us; speedup vs baseline: 1.3372x; 1.0100x over previous
//
#include <hip/hip_runtime.h>
#include <hip/hip_bf16.h>
#include <stdint.h>

typedef uint32_t u32;
typedef unsigned short u16;
typedef float v2f __attribute__((ext_vector_type(2)));

#define NLAT_I 361
#define NLON_I 720
#define NLAT_O 181
#define NLON_O 360
#define KK 9
#define NNZ 120000
#define NSEG (KK * NLAT_O)            /* 1629 */
#define NPIX (NLAT_O * NLON_O)        /* 65160 */
#define NCH 32
#define ROWLEN 5760                   /* u32 words per (hi,p) row: 360*16 */

/* stage1: r9 structure EXACTLY (the measured optimum, 220 us): 233 blocks x
   7 UNIFORM segs (r14's 7/6 rebalance regressed: barrier couples everyone
   to the 7-seg critical path), parallel acc[7][8], burst-4, NC=4 phases,
   launch_bounds(768,3). Sort is folded into the stage1 prologue (in-LDS
   rank sort), deleting the separate 1629-block sort dispatch. */
#define NBLK1 233
#define SEGS_PER_BLK 7
#define NC 4
#define LDSCAP 160                    /* staged recs per segment (max cnt ~110) */
#define SPIN_LIMIT 100

#define HIST_BLKS ((NNZ + 255) / 256) /* 469 */

__device__ __forceinline__ u32 f2bf_rne(float f) {
    u32 b = __float_as_uint(f);
    return (b + 0x7FFFu + ((b >> 16) & 1u)) >> 16;
}

__device__ __forceinline__ int imin(int a, int b) { return a < b ? a : b; }

// ---------------- fused: repack (blocks 0..360) | hist (blocks 361..829) ---
// repack: x[32][361][720] f32 -> xp[hi*2+p][j][cp] bf16x2 (LDS transpose).
// hist:   counts[seg]++ for all nnz (counts pre-zeroed by the memset).
__global__ __launch_bounds__(256) void repack_hist_kernel(const float* __restrict__ x,
                                                          u32* __restrict__ xp,
                                                          const int* __restrict__ ker,
                                                          const int* __restrict__ row,
                                                          int* __restrict__ counts) {
    int tid = threadIdx.x;
    if (blockIdx.x >= NLAT_I) {
        int e = (blockIdx.x - NLAT_I) * 256 + tid;
        if (e < NNZ) {
            int seg = ker[e] * NLAT_O + row[e];
            atomicAdd(&counts[seg], 1);
        }
        return;
    }
    __shared__ u16 tile[32][732];
    int hi = blockIdx.x;
    const size_t plane = (size_t)NLAT_I * NLON_I;
#pragma unroll 1
    for (int c = 0; c < NCH; c++) {
        for (int col = tid; col < NLON_I; col += 256) {
            tile[c][col] = (u16)f2bf_rne(x[c * plane + (size_t)hi * NLON_I + col]);
        }
    }
    __syncthreads();
    for (int wdx = tid; wdx < 2 * ROWLEN; wdx += 256) {
        int p = wdx / ROWLEN;
        int rem = wdx - p * ROWLEN;
        int j = rem >> 4;
        int cp = rem & 15;
        int col = 2 * j + p;
        u32 v = (u32)tile[2 * cp][col] | ((u32)tile[2 * cp + 1][col] << 16);
        xp[(size_t)(2 * hi + p) * ROWLEN + rem] = v;
    }
}

// ---------------- CSR scan -------------------------------------------------
__global__ __launch_bounds__(256) void scan_kernel(const int* __restrict__ counts,
                                                   int* __restrict__ offsets) {
    __shared__ int lsum[256];
    const int CH = 7;                  // 256*7 = 1792 >= 1629
    int t = threadIdx.x;
    int base = t * CH;
    int local[CH];
    int s = 0;
    for (int i = 0; i < CH; i++) {
        int v = (base + i < NSEG) ? counts[base + i] : 0;
        local[i] = s;
        s += v;
    }
    lsum[t] = s;
    __syncthreads();
    for (int off = 1; off < 256; off <<= 1) {
        int v = 0;
        if (t >= off) v = lsum[t - off];
        __syncthreads();
        if (t >= off) lsum[t] += v;
        __syncthreads();
    }
    int pre = (t == 0) ? 0 : lsum[t - 1];
    for (int i = 0; i < CH; i++) {
        if (base + i < NSEG) offsets[base + i] = pre + local[i];
    }
}

__global__ __launch_bounds__(256) void scatter_kernel(const int* __restrict__ ker,
                                                      const int* __restrict__ row,
                                                      const int* __restrict__ col,
                                                      const float* __restrict__ vals,
                                                      const int* __restrict__ offsets,
                                                      int* __restrict__ cursor,
                                                      int2* __restrict__ recs) {
    int e = blockIdx.x * 256 + threadIdx.x;
    if (e >= NNZ) return;
    int seg = ker[e] * NLAT_O + row[e];
    int pos = offsets[seg] + atomicAdd(&cursor[seg], 1);
    int c  = col[e];
    int hi = c / NLON_I;
    int wi = c % NLON_I;
    int p  = wi & 1;
    int a  = wi >> 1;                  // < 360
    u32 meta = ((u32)hi << 10) | ((u32)p << 9) | (u32)a;
    recs[pos] = make_int2((int)meta, __float_as_int(vals[e]));
}

// ---------------- stage1: persistent, channel-split, phase-synced ----------
// thread = (wo, channel-half). acc = v2f[7][8] (112 f32, AGPR half of the
// unified file). Inner loop: burst unroll-4 (8 independent dwordx4 in
// flight). DO NOT: rotate-pipeline (r8 spill), launch_bounds(,6) (r11 reg
// starve), burst-8 (r12 serialized), sched_barrier fence (r13 regression),
// non-uniform seg split (r14 regression). Prologue sorts lrec in LDS by
// (hi,p,a) -- replaces the old sort_kernel dispatch; phase c then sweeps
// the c-th sorted-hi chunk so co-resident blocks share an L2 window.

__device__ __forceinline__ v2f bf2(u32 u) {
    v2f r;
    r.x = __uint_as_float(u << 16);
    r.y = __uint_as_float(u & 0xFFFF0000u);
    return r;
}

__device__ __forceinline__ const uint4* entry_ptr(const u32* __restrict__ xph,
                                                  u32 m, int w) {
    int row = (int)(m >> 9);            // hi*2+p
    int a   = (int)(m & 0x1FF);
    int idx = a + w;
    idx = (idx >= NLON_O) ? idx - NLON_O : idx;
    return (const uint4*)(xph + ((size_t)(row * NLON_O + idx) << 4));
}

#define FMA8(q0, q1, vv, A)                 \
    {                                       \
        A[0] = bf2(q0.x) * vv + A[0];       \
        A[1] = bf2(q0.y) * vv + A[1];       \
        A[2] = bf2(q0.z) * vv + A[2];       \
        A[3] = bf2(q0.w) * vv + A[3];       \
        A[4] = bf2(q1.x) * vv + A[4];       \
        A[5] = bf2(q1.y) * vv + A[5];       \
        A[6] = bf2(q1.z) * vv + A[6];       \
        A[7] = bf2(q1.w) * vv + A[7];       \
    }

__device__ __forceinline__ void proc_range(const u32* __restrict__ xph,
                                           const int2* __restrict__ rec,
                                           int beg, int end, int w,
                                           v2f* __restrict__ A) {
    int i = beg;
#pragma unroll 1
    for (; i + 4 <= end; i += 4) {
        int2 r0 = rec[i];
        int2 r1 = rec[i + 1];
        int2 r2 = rec[i + 2];
        int2 r3 = rec[i + 3];
        const uint4* p0 = entry_ptr(xph, (u32)r0.x, w);
        const uint4* p1 = entry_ptr(xph, (u32)r1.x, w);
        const uint4* p2 = entry_ptr(xph, (u32)r2.x, w);
        const uint4* p3 = entry_ptr(xph, (u32)r3.x, w);
        uint4 a0 = p0[0]; uint4 a1 = p0[1];
        uint4 b0 = p1[0]; uint4 b1 = p1[1];
        uint4 c0 = p2[0]; uint4 c1 = p2[1];
        uint4 d0 = p3[0]; uint4 d1 = p3[1];
        v2f v0 = {__int_as_float(r0.y), __int_as_float(r0.y)};
        v2f v1 = {__int_as_float(r1.y), __int_as_float(r1.y)};
        v2f v2 = {__int_as_float(r2.y), __int_as_float(r2.y)};
        v2f v3 = {__int_as_float(r3.y), __int_as_float(r3.y)};
        FMA8(a0, a1, v0, A)
        FMA8(b0, b1, v1, A)
        FMA8(c0, c1, v2, A)
        FMA8(d0, d1, v3, A)
    }
#pragma unroll 1
    for (; i < end; ++i) {
        int2 r0 = rec[i];
        const uint4* p0 = entry_ptr(xph, (u32)r0.x, w);
        uint4 a0 = p0[0]; uint4 a1 = p0[1];
        v2f v0 = {__int_as_float(r0.y), __int_as_float(r0.y)};
        FMA8(a0, a1, v0, A)
    }
}

__global__ __launch_bounds__(768, 3) void stage1_kernel(const u32* __restrict__ xp,
                                                        const int* __restrict__ offs,
                                                        const int* __restrict__ cnts,
                                                        const int2* __restrict__ recs,
                                                        int* __restrict__ ctr,
                                                        u16* __restrict__ xk) {
    __shared__ int2 lrec[SEGS_PER_BLK][LDSCAP];
    __shared__ int scnt[SEGS_PER_BLK], soff[SEGS_PER_BLK];

    int b = blockIdx.x;
    int tid = threadIdx.x;

    if (tid < SEGS_PER_BLK) {
        int s = b * SEGS_PER_BLK + tid;
        int ok = (s < NSEG);
        scnt[tid] = ok ? cnts[s] : 0;
        soff[tid] = ok ? offs[s] : 0;
    }
    __syncthreads();

#pragma unroll
    for (int slot = 0; slot < SEGS_PER_BLK; slot++) {
        int c = imin(scnt[slot], LDSCAP);
        int o = soff[slot];
        for (int i = tid; i < c; i += 768) lrec[slot][i] = recs[o + i];
    }
    __syncthreads();

    // in-LDS rank sort per slot by meta (hi,p,a ascending). cnt<=160 < 768:
    // one element per thread; LDS reads of lrec[slot][j] are same-address
    // broadcasts (free). Replaces the old sort_kernel dispatch.
#pragma unroll 1
    for (int slot = 0; slot < SEGS_PER_BLK; slot++) {
        int cnt = imin(scnt[slot], LDSCAP);
        int2 myrec;
        int myrank = -1;
        if (tid < cnt) {
            myrec = lrec[slot][tid];
            u32 k = (u32)myrec.x;
            int rank = 0;
            for (int j = 0; j < cnt; j++) {
                u32 kj = (u32)lrec[slot][j].x;
                rank += (kj < k || (kj == k && j < tid)) ? 1 : 0;
            }
            myrank = rank;
        }
        __syncthreads();
        if (myrank >= 0) lrec[slot][myrank] = myrec;
    }
    __syncthreads();

    int wo = tid >> 1, h = tid & 1;
    bool act = wo < NLON_O;
    int w = act ? wo : 0;
    const u32* xph = xp + h * 8;

    v2f acc[SEGS_PER_BLK][8];
#pragma unroll
    for (int slot = 0; slot < SEGS_PER_BLK; slot++)
#pragma unroll
        for (int j = 0; j < 8; j++) acc[slot][j] = (v2f){0.0f, 0.0f};

    for (int c = 0; c < NC; c++) {
#pragma unroll
        for (int slot = 0; slot < SEGS_PER_BLK; slot++) {
            int cnt = scnt[slot];
            int beg = (c * cnt) / NC;
            int end = ((c + 1) * cnt) / NC;
            if (end <= LDSCAP) {
                proc_range(xph, lrec[slot], beg, end, w, acc[slot]);
            } else {
                proc_range(xph, recs + soff[slot], beg, end, w, acc[slot]);
            }
        }
        if (c < NC - 1) {
            // bounded-spin quasi-barrier: keeps all co-resident blocks on the
            // same sorted-hi chunk (~4 MB live xp slice -> per-XCD L2 hot).
            // Deadlock-free: spin capped; correctness never depends on it.
            __syncthreads();
            if (tid == 0) {
                __hip_atomic_fetch_add(&ctr[c], 1, __ATOMIC_RELAXED,
                                       __HIP_MEMORY_SCOPE_AGENT);
                int spins = 0;
                while (spins < SPIN_LIMIT &&
                       __hip_atomic_load(&ctr[c], __ATOMIC_RELAXED,
                                         __HIP_MEMORY_SCOPE_AGENT) < (int)gridDim.x) {
                    __builtin_amdgcn_s_sleep(2);
                    ++spins;
                }
            }
            __syncthreads();
        }
    }

    if (act) {
#pragma unroll
        for (int slot = 0; slot < SEGS_PER_BLK; slot++) {
            int s = b * SEGS_PER_BLK + slot;
            if (s < NSEG) {
                int k = s / NLAT_O;
                int ho = s - k * NLAT_O;
                int pix = ho * NLON_O + wo;
#pragma unroll
                for (int j = 0; j < 8; j++) {
                    int ch = h * 16 + 2 * j;
                    xk[(size_t)(ch * KK + k) * NPIX + pix] =
                        (u16)f2bf_rne(acc[slot][j].x);
                    xk[(size_t)((ch + 1) * KK + k) * NPIX + pix] =
                        (u16)f2bf_rne(acc[slot][j].y);
                }
            }
        }
    }
}

// ---------------- stage2: out[32][65160] = W[32][288] * xk[288][65160] -----
// K-split x4: block = 64 pix-pairs x 4 K-slices (72 r each), LDS reduce.
#define S2_PP 64
#define S2_RPK 72                     /* 288 / 4 */

__global__ __launch_bounds__(256) void stage2_kernel(const u16* __restrict__ xk,
                                                     const float* __restrict__ W,
                                                     const float* __restrict__ bias,
                                                     float* __restrict__ out) {
    __shared__ float2 red[4][S2_PP][17];   // 4*64*17*8 = 34816 B
    int pp  = threadIdx.x & 63;
    int ksl = threadIdx.x >> 6;            // 0..3
    int px2 = blockIdx.x * S2_PP + pp;     // pix-pair id
    bool act = px2 < NPIX / 2;
    int px = act ? px2 : 0;
    const u32* xk32 = (const u32*)xk;

    float a0[NCH], a1[NCH];
#pragma unroll
    for (int o = 0; o < NCH; o++) { a0[o] = 0.0f; a1[o] = 0.0f; }

    int rbase = ksl * S2_RPK;
#pragma unroll 4
    for (int rr = 0; rr < S2_RPK; rr++) {
        int r = rbase + rr;
        u32 u = xk32[(size_t)r * (NPIX / 2) + px];
        float x0 = __uint_as_float(u << 16);
        float x1 = __uint_as_float(u & 0xFFFF0000u);
#pragma unroll
        for (int o = 0; o < NCH; o++) {
            float wv = W[o * (NCH * KK) + r];
            a0[o] = fmaf(wv, x0, a0[o]);
            a1[o] = fmaf(wv, x1, a1[o]);
        }
    }

    // reduce the 4 K-slices via LDS, in 2 half-passes of 16 outputs each
#pragma unroll 1
    for (int half = 0; half < 2; half++) {
        __syncthreads();
#pragma unroll
        for (int j = 0; j < 16; j++) {
            int o = half * 16 + j;
            red[ksl][pp][j] = make_float2(a0[o], a1[o]);
        }
        __syncthreads();
        // wave ksl now handles outputs [ksl*4, ksl*4+4) of this half
#pragma unroll
        for (int j = 0; j < 4; j++) {
            int oo = ksl * 4 + j;
            float2 s0 = red[0][pp][oo];
            float2 s1 = red[1][pp][oo];
            float2 s2 = red[2][pp][oo];
            float2 s3 = red[3][pp][oo];
            float sx = s0.x + s1.x + s2.x + s3.x;
            float sy = s0.y + s1.y + s2.y + s3.y;
            int o = half * 16 + oo;
            if (act) {
                float bv = bias[o];
                float2 v = make_float2(sx + bv, sy + bv);
                *(float2*)(out + (size_t)o * NPIX + 2 * px2) = v;
            }
        }
    }
}

// ---------------- launch ---------------------------------------------------
extern "C" void kernel_launch(void* const* d_in, const int* in_sizes, int n_in,
                              void* d_out, int out_size, void* d_ws, size_t ws_size,
                              hipStream_t stream) {
    const float* x    = (const float*)d_in[0];
    const int* ker    = (const int*)d_in[1];
    const int* row    = (const int*)d_in[2];
    const int* col    = (const int*)d_in[3];
    const float* vals = (const float*)d_in[4];
    const float* W    = (const float*)d_in[5];
    const float* bias = (const float*)d_in[6];
    float* out        = (float*)d_out;

    char* ws = (char*)d_ws;
    const size_t off_xp   = 0;
    const size_t sz_xp    = (size_t)NLAT_I * 2 * ROWLEN * 4;   // 16,634,880
    const size_t off_cnt  = off_xp + sz_xp;
    const size_t off_off  = off_cnt + 6528;
    const size_t off_cur  = off_off + 6528;
    const size_t off_ctr  = off_cur + 6528;                    // 64 B (ctr ints)
    const size_t off_rec  = off_ctr + 64;                      // 8-aligned
    const size_t off_xk   = off_rec + (size_t)NNZ * 8;

    u32* xp      = (u32*)(ws + off_xp);
    int* counts  = (int*)(ws + off_cnt);
    int* offsets = (int*)(ws + off_off);
    int* cursor  = (int*)(ws + off_cur);
    int* ctr     = (int*)(ws + off_ctr);
    int2* recs   = (int2*)(ws + off_rec);
    u16* xk      = (u16*)(ws + off_xk);

    // zero counts + offsets + cursor + barrier counters (must precede the
    // fused hist atomics -- cannot be folded into that kernel)
    hipMemsetAsync(ws + off_cnt, 0, 3 * 6528 + 64, stream);

    repack_hist_kernel<<<NLAT_I + HIST_BLKS, 256, 0, stream>>>(x, xp, ker, row, counts);
    scan_kernel<<<1, 256, 0, stream>>>(counts, offsets);
    scatter_kernel<<<HIST_BLKS, 256, 0, stream>>>(ker, row, col, vals,
                                                  offsets, cursor, recs);
    stage1_kernel<<<NBLK1, 768, 0, stream>>>(xp, offsets, counts, recs, ctr, xk);
    stage2_kernel<<<(NPIX / 2 + S2_PP - 1) / S2_PP, 256, 0, stream>>>(xk, W, bias, out);
}

// Round 16
// 344.110 us; speedup vs baseline: 1.3442x; 1.0053x over previous
//
#include <hip/hip_runtime.h>
#include <hip/hip_bf16.h>
#include <stdint.h>

typedef uint32_t u32;
typedef unsigned short u16;
typedef float v2f __attribute__((ext_vector_type(2)));

#define NLAT_I 361
#define NLON_I 720
#define NLAT_O 181
#define NLON_O 360
#define KK 9
#define NNZ 120000
#define NSEG (KK * NLAT_O)            /* 1629 */
#define NPIX (NLAT_O * NLON_O)        /* 65160 */
#define NCH 32
#define ROWLEN 5760                   /* u32 words per (hi,p) row: 360*16 */

/* stage1: r9 structure (233 blocks x 7 uniform segs, acc[7][8], burst-4,
   NC=4 phases, launch_bounds(768,3)) -- the measured optimum. CSR build
   (hist/scan/scatter) is DELETED: each block self-gathers its 7 segments
   from the packed entry list (960 KB, L2/L3-resident) in the prologue.
   6 dispatches -> 3: boundary overhead was ~12 us per dispatch. */
#define NBLK1 233
#define SEGS_PER_BLK 7
#define NC 4
#define CAP 320                       /* entries/segment LDS cap (mean 74, 21 sigma) */
#define SPIN_LIMIT 100

#define PACK_BLKS ((NNZ + 255) / 256) /* 469 */

__device__ __forceinline__ u32 f2bf_rne(float f) {
    u32 b = __float_as_uint(f);
    return (b + 0x7FFFu + ((b >> 16) & 1u)) >> 16;
}

__device__ __forceinline__ int imin(int a, int b) { return a < b ? a : b; }

// ---- fused front: repack (blocks 0..360) | entry-pack + ctr-zero (rest) ---
// repack: x[32][361][720] f32 -> xp[hi*2+p][j][cp] bf16x2 (LDS transpose).
// pack:   recs2[e] = { seg(11b)<<19 | hi(9b)<<10 | p<<9 | a(9b), val }.
__global__ __launch_bounds__(256) void front_kernel(const float* __restrict__ x,
                                                    u32* __restrict__ xp,
                                                    const int* __restrict__ ker,
                                                    const int* __restrict__ row,
                                                    const int* __restrict__ col,
                                                    const float* __restrict__ vals,
                                                    int2* __restrict__ recs2,
                                                    int* __restrict__ ctr) {
    int tid = threadIdx.x;
    if (blockIdx.x >= NLAT_I) {
        int pb = blockIdx.x - NLAT_I;
        if (pb == 0 && tid < 16) ctr[tid] = 0;
        int e = pb * 256 + tid;
        if (e < NNZ) {
            int seg = ker[e] * NLAT_O + row[e];
            int c = col[e];
            int hi = c / NLON_I;
            int wi = c - hi * NLON_I;
            int p = wi & 1;
            int a = wi >> 1;
            u32 key = ((u32)seg << 19) | ((u32)hi << 10) | ((u32)p << 9) | (u32)a;
            recs2[e] = make_int2((int)key, __float_as_int(vals[e]));
        }
        return;
    }
    __shared__ u16 tile[32][732];
    int hi = blockIdx.x;
    const size_t plane = (size_t)NLAT_I * NLON_I;
#pragma unroll 1
    for (int c = 0; c < NCH; c++) {
        for (int cl = tid; cl < NLON_I; cl += 256) {
            tile[c][cl] = (u16)f2bf_rne(x[c * plane + (size_t)hi * NLON_I + cl]);
        }
    }
    __syncthreads();
    for (int wdx = tid; wdx < 2 * ROWLEN; wdx += 256) {
        int p = wdx / ROWLEN;
        int rem = wdx - p * ROWLEN;
        int j = rem >> 4;
        int cp = rem & 15;
        int cl = 2 * j + p;
        u32 v = (u32)tile[2 * cp][cl] | ((u32)tile[2 * cp + 1][cl] << 16);
        xp[(size_t)(2 * hi + p) * ROWLEN + rem] = v;
    }
}

// ---------------- stage1: persistent, self-gathering, phase-synced ---------
// thread = (wo, channel-half). acc = v2f[7][8] (112 f32, AGPR half). Inner
// loop: burst unroll-4 (8 independent dwordx4 in flight). DO NOT: rotate-
// pipeline (r8 spill), launch_bounds(,6) (r11 reg starve), burst-8 (r12
// serialized), sched_barrier fence (r13), non-uniform seg split (r14).
// Prologue: scan the 960KB packed list, extract own 7 segs to LDS (atomic
// slot counters), in-LDS rank sort by (hi,p,a) -> sorted-phase sweep.

__device__ __forceinline__ v2f bf2(u32 u) {
    v2f r;
    r.x = __uint_as_float(u << 16);
    r.y = __uint_as_float(u & 0xFFFF0000u);
    return r;
}

__device__ __forceinline__ const uint4* entry_ptr(const u32* __restrict__ xph,
                                                  u32 m, int w) {
    int row = (int)(m >> 9);            // hi*2+p
    int a   = (int)(m & 0x1FF);
    int idx = a + w;
    idx = (idx >= NLON_O) ? idx - NLON_O : idx;
    return (const uint4*)(xph + ((size_t)(row * NLON_O + idx) << 4));
}

#define FMA8(q0, q1, vv, A)                 \
    {                                       \
        A[0] = bf2(q0.x) * vv + A[0];       \
        A[1] = bf2(q0.y) * vv + A[1];       \
        A[2] = bf2(q0.z) * vv + A[2];       \
        A[3] = bf2(q0.w) * vv + A[3];       \
        A[4] = bf2(q1.x) * vv + A[4];       \
        A[5] = bf2(q1.y) * vv + A[5];       \
        A[6] = bf2(q1.z) * vv + A[6];       \
        A[7] = bf2(q1.w) * vv + A[7];       \
    }

__device__ __forceinline__ void proc_range(const u32* __restrict__ xph,
                                           const int2* __restrict__ rec,
                                           int beg, int end, int w,
                                           v2f* __restrict__ A) {
    int i = beg;
#pragma unroll 1
    for (; i + 4 <= end; i += 4) {
        int2 r0 = rec[i];
        int2 r1 = rec[i + 1];
        int2 r2 = rec[i + 2];
        int2 r3 = rec[i + 3];
        const uint4* p0 = entry_ptr(xph, (u32)r0.x, w);
        const uint4* p1 = entry_ptr(xph, (u32)r1.x, w);
        const uint4* p2 = entry_ptr(xph, (u32)r2.x, w);
        const uint4* p3 = entry_ptr(xph, (u32)r3.x, w);
        uint4 a0 = p0[0]; uint4 a1 = p0[1];
        uint4 b0 = p1[0]; uint4 b1 = p1[1];
        uint4 c0 = p2[0]; uint4 c1 = p2[1];
        uint4 d0 = p3[0]; uint4 d1 = p3[1];
        v2f v0 = {__int_as_float(r0.y), __int_as_float(r0.y)};
        v2f v1 = {__int_as_float(r1.y), __int_as_float(r1.y)};
        v2f v2 = {__int_as_float(r2.y), __int_as_float(r2.y)};
        v2f v3 = {__int_as_float(r3.y), __int_as_float(r3.y)};
        FMA8(a0, a1, v0, A)
        FMA8(b0, b1, v1, A)
        FMA8(c0, c1, v2, A)
        FMA8(d0, d1, v3, A)
    }
#pragma unroll 1
    for (; i < end; ++i) {
        int2 r0 = rec[i];
        const uint4* p0 = entry_ptr(xph, (u32)r0.x, w);
        uint4 a0 = p0[0]; uint4 a1 = p0[1];
        v2f v0 = {__int_as_float(r0.y), __int_as_float(r0.y)};
        FMA8(a0, a1, v0, A)
    }
}

__global__ __launch_bounds__(768, 3) void stage1_kernel(const u32* __restrict__ xp,
                                                        const int2* __restrict__ recs2,
                                                        int* __restrict__ ctr,
                                                        u16* __restrict__ xk) {
    __shared__ int2 lrec[SEGS_PER_BLK][CAP];   // 17,920 B
    __shared__ int lcnt[8];

    int b = blockIdx.x;
    int tid = threadIdx.x;
    int base = b * SEGS_PER_BLK;

    if (tid < 8) lcnt[tid] = 0;
    __syncthreads();

    // self-gather: scan the packed entry list (coalesced, L2/L3-resident),
    // keep entries whose seg is in [base, base+7)
#pragma unroll 4
    for (int e = tid; e < NNZ; e += 768) {
        int2 r = recs2[e];
        int seg = (int)(((u32)r.x) >> 19);
        unsigned rel = (unsigned)(seg - base);
        if (rel < (unsigned)SEGS_PER_BLK) {
            int pos = atomicAdd(&lcnt[rel], 1);
            if (pos < CAP)
                lrec[rel][pos] = make_int2((int)(((u32)r.x) & 0x7FFFFu), r.y);
        }
    }
    __syncthreads();

    // in-LDS rank sort per slot by (hi,p,a). cnt <= CAP < 768: one element
    // per thread; rank-loop reads are same-address broadcasts. Restores the
    // deterministic sorted order (and the sorted-phase L2 window).
#pragma unroll 1
    for (int slot = 0; slot < SEGS_PER_BLK; slot++) {
        int cnt = imin(lcnt[slot], CAP);
        int2 myrec;
        int myrank = -1;
        if (tid < cnt) {
            myrec = lrec[slot][tid];
            u32 k = (u32)myrec.x;
            int rank = 0;
            for (int j = 0; j < cnt; j++) {
                u32 kj = (u32)lrec[slot][j].x;
                rank += (kj < k || (kj == k && j < tid)) ? 1 : 0;
            }
            myrank = rank;
        }
        __syncthreads();
        if (myrank >= 0) lrec[slot][myrank] = myrec;
    }
    __syncthreads();

    int wo = tid >> 1, h = tid & 1;
    bool act = wo < NLON_O;
    int w = act ? wo : 0;
    const u32* xph = xp + h * 8;

    v2f acc[SEGS_PER_BLK][8];
#pragma unroll
    for (int slot = 0; slot < SEGS_PER_BLK; slot++)
#pragma unroll
        for (int j = 0; j < 8; j++) acc[slot][j] = (v2f){0.0f, 0.0f};

    for (int c = 0; c < NC; c++) {
#pragma unroll
        for (int slot = 0; slot < SEGS_PER_BLK; slot++) {
            int cnt = imin(lcnt[slot], CAP);
            int beg = (c * cnt) / NC;
            int end = ((c + 1) * cnt) / NC;
            proc_range(xph, lrec[slot], beg, end, w, acc[slot]);
        }
        if (c < NC - 1) {
            // bounded-spin quasi-barrier: keeps all co-resident blocks on the
            // same sorted-hi chunk (~4 MB live xp slice -> per-XCD L2 hot).
            // Deadlock-free: spin capped; correctness never depends on it.
            __syncthreads();
            if (tid == 0) {
                __hip_atomic_fetch_add(&ctr[c], 1, __ATOMIC_RELAXED,
                                       __HIP_MEMORY_SCOPE_AGENT);
                int spins = 0;
                while (spins < SPIN_LIMIT &&
                       __hip_atomic_load(&ctr[c], __ATOMIC_RELAXED,
                                         __HIP_MEMORY_SCOPE_AGENT) < (int)gridDim.x) {
                    __builtin_amdgcn_s_sleep(2);
                    ++spins;
                }
            }
            __syncthreads();
        }
    }

    if (act) {
#pragma unroll
        for (int slot = 0; slot < SEGS_PER_BLK; slot++) {
            int s = base + slot;
            if (s < NSEG) {
                int k = s / NLAT_O;
                int ho = s - k * NLAT_O;
                int pix = ho * NLON_O + wo;
#pragma unroll
                for (int j = 0; j < 8; j++) {
                    int ch = h * 16 + 2 * j;
                    xk[(size_t)(ch * KK + k) * NPIX + pix] =
                        (u16)f2bf_rne(acc[slot][j].x);
                    xk[(size_t)((ch + 1) * KK + k) * NPIX + pix] =
                        (u16)f2bf_rne(acc[slot][j].y);
                }
            }
        }
    }
}

// ---------------- stage2: out[32][65160] = W[32][288] * xk[288][65160] -----
// K-split x4: block = 64 pix-pairs x 4 K-slices (72 r each), LDS reduce.
#define S2_PP 64
#define S2_RPK 72                     /* 288 / 4 */

__global__ __launch_bounds__(256) void stage2_kernel(const u16* __restrict__ xk,
                                                     const float* __restrict__ W,
                                                     const float* __restrict__ bias,
                                                     float* __restrict__ out) {
    __shared__ float2 red[4][S2_PP][17];   // 4*64*17*8 = 34816 B
    int pp  = threadIdx.x & 63;
    int ksl = threadIdx.x >> 6;            // 0..3
    int px2 = blockIdx.x * S2_PP + pp;     // pix-pair id
    bool act = px2 < NPIX / 2;
    int px = act ? px2 : 0;
    const u32* xk32 = (const u32*)xk;

    float a0[NCH], a1[NCH];
#pragma unroll
    for (int o = 0; o < NCH; o++) { a0[o] = 0.0f; a1[o] = 0.0f; }

    int rbase = ksl * S2_RPK;
#pragma unroll 4
    for (int rr = 0; rr < S2_RPK; rr++) {
        int r = rbase + rr;
        u32 u = xk32[(size_t)r * (NPIX / 2) + px];
        float x0 = __uint_as_float(u << 16);
        float x1 = __uint_as_float(u & 0xFFFF0000u);
#pragma unroll
        for (int o = 0; o < NCH; o++) {
            float wv = W[o * (NCH * KK) + r];
            a0[o] = fmaf(wv, x0, a0[o]);
            a1[o] = fmaf(wv, x1, a1[o]);
        }
    }

    // reduce the 4 K-slices via LDS, in 2 half-passes of 16 outputs each
#pragma unroll 1
    for (int half = 0; half < 2; half++) {
        __syncthreads();
#pragma unroll
        for (int j = 0; j < 16; j++) {
            int o = half * 16 + j;
            red[ksl][pp][j] = make_float2(a0[o], a1[o]);
        }
        __syncthreads();
        // wave ksl now handles outputs [ksl*4, ksl*4+4) of this half
#pragma unroll
        for (int j = 0; j < 4; j++) {
            int oo = ksl * 4 + j;
            float2 s0 = red[0][pp][oo];
            float2 s1 = red[1][pp][oo];
            float2 s2 = red[2][pp][oo];
            float2 s3 = red[3][pp][oo];
            float sx = s0.x + s1.x + s2.x + s3.x;
            float sy = s0.y + s1.y + s2.y + s3.y;
            int o = half * 16 + oo;
            if (act) {
                float bv = bias[o];
                float2 v = make_float2(sx + bv, sy + bv);
                *(float2*)(out + (size_t)o * NPIX + 2 * px2) = v;
            }
        }
    }
}

// ---------------- launch ---------------------------------------------------
extern "C" void kernel_launch(void* const* d_in, const int* in_sizes, int n_in,
                              void* d_out, int out_size, void* d_ws, size_t ws_size,
                              hipStream_t stream) {
    const float* x    = (const float*)d_in[0];
    const int* ker    = (const int*)d_in[1];
    const int* row    = (const int*)d_in[2];
    const int* col    = (const int*)d_in[3];
    const float* vals = (const float*)d_in[4];
    const float* W    = (const float*)d_in[5];
    const float* bias = (const float*)d_in[6];
    float* out        = (float*)d_out;

    char* ws = (char*)d_ws;
    const size_t off_xp  = 0;
    const size_t sz_xp   = (size_t)NLAT_I * 2 * ROWLEN * 4;    // 16,634,880
    const size_t off_ctr = off_xp + sz_xp;                     // 64 B
    const size_t off_rec = off_ctr + 64;                       // 8-aligned
    const size_t off_xk  = off_rec + (size_t)NNZ * 8;

    u32* xp    = (u32*)(ws + off_xp);
    int* ctr   = (int*)(ws + off_ctr);
    int2* recs2 = (int2*)(ws + off_rec);
    u16* xk    = (u16*)(ws + off_xk);

    // 3-dispatch chain; ctr zeroing is inside front_kernel (stream-ordered
    // before stage1), CSR build is gone (stage1 self-gathers).
    front_kernel<<<NLAT_I + PACK_BLKS, 256, 0, stream>>>(x, xp, ker, row, col,
                                                         vals, recs2, ctr);
    stage1_kernel<<<NBLK1, 768, 0, stream>>>(xp, recs2, ctr, xk);
    stage2_kernel<<<(NPIX / 2 + S2_PP - 1) / S2_PP, 256, 0, stream>>>(xk, W, bias, out);
}